// Round 9
// baseline (4746.924 us; speedup 1.0000x reference)
//
#include <hip/hip_runtime.h>
#include <hip/hip_fp16.h>
#include <hip/hip_cooperative_groups.h>

namespace cg = cooperative_groups;

typedef _Float16 half8 __attribute__((ext_vector_type(8)));
typedef float floatx4 __attribute__((ext_vector_type(4)));

#define NB 128
#define NT 256
#define NIN 128
#define NH 1024

// ws layout (bytes): 8-deep h rings + fp16 x copy + barrier state
#define H0_OFF   0u          // 8 bufs x 128*1024 half = 2097152 B
#define H1_OFF   2097152u    // 2097152 B
#define X16_OFF  4194304u    // 128*256*128 half = 8388608 B
#define BAR_OFF  12582912u   // 16 group lines @256B, root @4096, flag @4352

// LDS layout (bytes). Weights in FRAGMENT ORDER: element (mat, s, lane) holds
// the 16B half8 B-fragment for MFMA step s, lane l — ds_read addr = lane*16B,
// perfectly bank-tiled (zero >2-way conflicts).
#define W0X_OFF  0        // x->gates0:  4 steps * 64 * 16B = 4096
#define W0H_OFF  4096     // h0->gates0: 32 steps * 64 * 16B = 32768
#define W1I_OFF  36864    // h0->gates1: 32768
#define W1H_OFF  69632    // h1->gates1: 32768
#define PS0_OFF  102400   // partial gates0: [2 kc][16 col][129] f32 = 16512
#define PS1_OFF  118912   // partial gates1: 16512
#define BS_OFF   135424   // bs0[16], bs1[16] f32 = 128
#define LDS_BYTES 135552

#define MFMA16(a, b, c) __builtin_amdgcn_mfma_f32_16x16x32_f16((a), (b), (c), 0, 0, 0)

__device__ __forceinline__ float sigm(float x) { return 1.0f / (1.0f + __expf(-x)); }
__device__ __forceinline__ float tanh_fast(float x) { return 1.0f - 2.0f / (__expf(2.0f * x) + 1.0f); }

// h STORES: agent-scope relaxed atomic 2B stores — write-through past the
// non-coherent XCD L2 to LLC. After __syncthreads' vmcnt(0) drain these are
// globally visible: NO release (wbl2) fence needed (validated R5-R8).
__device__ __forceinline__ void st2_agent(_Float16* p, float v) {
    _Float16 hv = (_Float16)v;
    unsigned short u;
    __builtin_memcpy(&u, &hv, 2);
    __hip_atomic_store((unsigned short*)p, u, __ATOMIC_RELAXED, __HIP_MEMORY_SCOPE_AGENT);
}

// Two-level grid barrier (16 groups x 16 WGs, separate LLC lines).
// Acquire side ring-aware: full agent inv (L1+XCD L2) only every 8th epoch
// (ring-address reuse boundary); cheap L1-only inv otherwise (validated R8).
__device__ __forceinline__ void gbar_arrive(char* bar, unsigned epoch, int wg) {
    unsigned* gcnt = (unsigned*)(bar + (wg & 15) * 256);
    unsigned old = __hip_atomic_fetch_add(gcnt, 1u, __ATOMIC_RELAXED, __HIP_MEMORY_SCOPE_AGENT);
    if (old == epoch * 16u - 1u) {
        unsigned* rcnt = (unsigned*)(bar + 4096);
        unsigned rold = __hip_atomic_fetch_add(rcnt, 1u, __ATOMIC_RELAXED, __HIP_MEMORY_SCOPE_AGENT);
        if (rold == epoch * 16u - 1u) {
            unsigned* flag = (unsigned*)(bar + 4352);
            __hip_atomic_store(flag, epoch, __ATOMIC_RELAXED, __HIP_MEMORY_SCOPE_AGENT);
        }
    }
}
__device__ __forceinline__ void gbar_wait(char* bar, unsigned epoch) {
    unsigned* flag = (unsigned*)(bar + 4352);
    while (__hip_atomic_load(flag, __ATOMIC_RELAXED, __HIP_MEMORY_SCOPE_AGENT) < epoch)
        __builtin_amdgcn_s_sleep(1);
    if ((epoch & 7u) == 0u) {
        __builtin_amdgcn_fence(__ATOMIC_ACQUIRE, "agent");
    } else {
        asm volatile("s_waitcnt vmcnt(0)\n\tbuffer_inv sc0" ::: "memory");
    }
}

__global__ void __launch_bounds__(512)
lstm_persist(const float* __restrict__ x,
             const float* __restrict__ Wih0, const float* __restrict__ Whh0,
             const float* __restrict__ bih0, const float* __restrict__ bhh0,
             const float* __restrict__ Wih1, const float* __restrict__ Whh1,
             const float* __restrict__ bih1, const float* __restrict__ bhh1,
             const float* __restrict__ Wd, const float* __restrict__ bd,
             float* __restrict__ out, char* __restrict__ wsc)
{
    cg::grid_group grid = cg::this_grid();
    const int wg   = blockIdx.x;      // 0..255, owns h-cols [wg*4, wg*4+4)
    const int tid  = threadIdx.x;     // 0..511
    const int wave = tid >> 6;        // 0..7
    const int lane = tid & 63;
    const int l15  = lane & 15;
    const int quad = lane >> 4;
    const int kc   = wave & 1;        // K-half: k in [kc*512, kc*512+512)
    const int rh   = wave >> 1;       // row quarter: rows [rh*32, rh*32+32), 2 tiles

    _Float16* h0b = (_Float16*)(wsc + H0_OFF);   // [8][128][1024] ring
    _Float16* h1b = (_Float16*)(wsc + H1_OFF);   // [8][128][1024] ring
    _Float16* x16 = (_Float16*)(wsc + X16_OFF);  // [128][256][128]
    char* bar = wsc + BAR_OFF;

    extern __shared__ char smem[];
    half8* w0x = (half8*)(smem + W0X_OFF);
    half8* w0h = (half8*)(smem + W0H_OFF);
    half8* w1i = (half8*)(smem + W1I_OFF);
    half8* w1h = (half8*)(smem + W1H_OFF);
    float* ps0 = (float*)(smem + PS0_OFF);       // [2][16][129]
    float* ps1 = (float*)(smem + PS1_OFF);
    float* bs0 = (float*)(smem + BS_OFF);
    float* bs1 = (float*)(smem + BS_OFF + 64);

    // ---------- init: stage weights in fragment order (fp16) ----------
    // unit u = one half8 fragment element (mat, s, ln): value[j] = W[gcol(ln&15)][s*32 + (ln>>4)*8 + j]
    for (int u = tid; u < 6400; u += 512) {
        const float* src; half8* dst; int idx; int K;
        if (u < 256)       { src = Wih0; dst = w0x; idx = u;        K = NIN; }
        else if (u < 2304) { src = Whh0; dst = w0h; idx = u - 256;  K = NH; }
        else if (u < 4352) { src = Wih1; dst = w1i; idx = u - 2304; K = NH; }
        else               { src = Whh1; dst = w1h; idx = u - 4352; K = NH; }
        int ln = idx & 63, s = idx >> 6;
        int col = ln & 15, q = ln >> 4;
        int gcol = ((col >> 2) << 10) + (wg << 2) + (col & 3);
        const float* sp = src + (size_t)gcol * K + s * 32 + q * 8;
        half8 v;
        #pragma unroll
        for (int j = 0; j < 8; ++j) v[j] = (_Float16)sp[j];
        dst[idx] = v;
    }
    if (tid < 16) {
        int c = tid;
        int gcol = ((c >> 2) << 10) + (wg << 2) + (c & 3);
        bs0[c] = bih0[gcol] + bhh0[gcol];
        bs1[c] = bih1[gcol] + bhh1[gcol];
    }

    // ---------- init: zero h rings, convert x to fp16, reset barrier ----------
    {
        const int gtid = wg * 512 + tid;
        const int gsz  = 256 * 512;
        float* hz = (float*)wsc;     // both rings = 4 MiB = 1048576 floats
        for (int i = gtid; i < 1048576; i += gsz) hz[i] = 0.0f;
        for (int i = gtid; i < NB * NT * NIN; i += gsz) x16[i] = (_Float16)x[i];
        if (wg == 0 && tid < 18) {
            if (tid < 16)       *(unsigned*)(bar + tid * 256) = 0u;
            else if (tid == 16) *(unsigned*)(bar + 4096) = 0u;
            else                *(unsigned*)(bar + 4352) = 0u;
        }
    }
    __builtin_amdgcn_fence(__ATOMIC_RELEASE, "agent");
    grid.sync();
    __builtin_amdgcn_fence(__ATOMIC_ACQUIRE, "agent");

    float c0 = 0.0f, c1 = 0.0f;          // persistent cell state per (b,hcol)
    const int b_act = tid >> 2;
    const int jl    = tid & 3;
    const int hcol  = (wg << 2) + jl;

    // x-part for step p, this wave's (kc, rh) share: xk = kc*64 + sx*32, 2 tiles
    floatx4 accx0 = {0.f, 0.f, 0.f, 0.f}, accx1 = {0.f, 0.f, 0.f, 0.f};
    auto xpart = [&](int p) {
        accx0 = floatx4{0.f, 0.f, 0.f, 0.f};
        accx1 = floatx4{0.f, 0.f, 0.f, 0.f};
        const _Float16* xb = x16 + (size_t)(rh * 32 + l15) * (NT * NIN) + p * NIN + kc * 64 + quad * 8;
        #pragma unroll
        for (int sx = 0; sx < 2; ++sx) {
            half8 xa0 = *(const half8*)(xb + sx * 32);
            half8 xa1 = *(const half8*)(xb + (size_t)16 * (NT * NIN) + sx * 32);
            half8 bf  = w0x[(kc * 2 + sx) * 64 + lane];
            accx0 = MFMA16(xa0, bf, accx0);
            accx1 = MFMA16(xa1, bf, accx1);
        }
    };
    xpart(0);   // prologue for p=0

    const int pbase = kc * 2064 + l15 * 129 + rh * 32 + quad * 4;  // ps float index

    // pipeline: phase p computes h0[p] (p<NT) and h1[p-1] (p>=1)
    // ring reads: h0[p-1] -> buf (p+7)&7 ; h1[p-2] -> buf (p+6)&7 (zeros pre-start)
    for (int p = 0; p <= NT; ++p) {
        const _Float16* h0prev = h0b + (size_t)((p + 7) & 7) * (NB * NH);
        const _Float16* h1pp   = h1b + (size_t)((p + 6) & 7) * (NB * NH);

        const _Float16* A0b = h0prev + (size_t)(rh * 32 + l15) * NH + kc * 512 + quad * 8;
        const _Float16* A1b = h1pp   + (size_t)(rh * 32 + l15) * NH + kc * 512 + quad * 8;
        const half8* B0 = w0h + (kc * 16) * 64 + lane;
        const half8* B1 = w1i + (kc * 16) * 64 + lane;
        const half8* B2 = w1h + (kc * 16) * 64 + lane;

        if (p >= 1 && p < NT) {
            floatx4 a00 = accx0, a01 = accx1;                       // layer0 (x-part preloaded)
            floatx4 a10 = {0.f,0.f,0.f,0.f}, a11 = {0.f,0.f,0.f,0.f};  // layer1 ih
            floatx4 a20 = {0.f,0.f,0.f,0.f}, a21 = {0.f,0.f,0.f,0.f};  // layer1 hh
            #pragma unroll
            for (int s = 0; s < 16; ++s) {
                half8 x00 = *(const half8*)(A0b + s * 32);
                half8 x01 = *(const half8*)(A0b + (size_t)16 * NH + s * 32);
                half8 x10 = *(const half8*)(A1b + s * 32);
                half8 x11 = *(const half8*)(A1b + (size_t)16 * NH + s * 32);
                half8 b0 = B0[s * 64], b1 = B1[s * 64], b2 = B2[s * 64];
                a00 = MFMA16(x00, b0, a00);  a01 = MFMA16(x01, b0, a01);
                a10 = MFMA16(x00, b1, a10);  a11 = MFMA16(x01, b1, a11);
                a20 = MFMA16(x10, b2, a20);  a21 = MFMA16(x11, b2, a21);
            }
            a10 = a10 + a20;  a11 = a11 + a21;
            *(floatx4*)(ps0 + pbase)      = a00;
            *(floatx4*)(ps0 + pbase + 16) = a01;
            *(floatx4*)(ps1 + pbase)      = a10;
            *(floatx4*)(ps1 + pbase + 16) = a11;
        } else if (p == 0) {   // h rings are zeros: gates0 = x-part only
            *(floatx4*)(ps0 + pbase)      = accx0;
            *(floatx4*)(ps0 + pbase + 16) = accx1;
        } else {               // p == NT: layer1 only
            floatx4 a10 = {0.f,0.f,0.f,0.f}, a11 = {0.f,0.f,0.f,0.f};
            floatx4 a20 = {0.f,0.f,0.f,0.f}, a21 = {0.f,0.f,0.f,0.f};
            #pragma unroll
            for (int s = 0; s < 16; ++s) {
                half8 x00 = *(const half8*)(A0b + s * 32);
                half8 x01 = *(const half8*)(A0b + (size_t)16 * NH + s * 32);
                half8 x10 = *(const half8*)(A1b + s * 32);
                half8 x11 = *(const half8*)(A1b + (size_t)16 * NH + s * 32);
                half8 b1 = B1[s * 64], b2 = B2[s * 64];
                a10 = MFMA16(x00, b1, a10);  a11 = MFMA16(x01, b1, a11);
                a20 = MFMA16(x10, b2, a20);  a21 = MFMA16(x11, b2, a21);
            }
            a10 = a10 + a20;  a11 = a11 + a21;
            *(floatx4*)(ps1 + pbase)      = a10;
            *(floatx4*)(ps1 + pbase + 16) = a11;
        }
        __syncthreads();

        // activation: thread (b_act, jl); gate value = sum of 2 kc partials + bias
        if (p < NT) {
            float gi = ps0[(jl)      * 129 + b_act] + ps0[2064 + (jl)      * 129 + b_act] + bs0[jl];
            float gf = ps0[(4 + jl)  * 129 + b_act] + ps0[2064 + (4 + jl)  * 129 + b_act] + bs0[4 + jl];
            float gg = ps0[(8 + jl)  * 129 + b_act] + ps0[2064 + (8 + jl)  * 129 + b_act] + bs0[8 + jl];
            float go = ps0[(12 + jl) * 129 + b_act] + ps0[2064 + (12 + jl) * 129 + b_act] + bs0[12 + jl];
            c0 = sigm(gf) * c0 + sigm(gi) * tanh_fast(gg);
            float h = sigm(go) * tanh_fast(c0);
            st2_agent(h0b + (size_t)(p & 7) * (NB * NH) + b_act * NH + hcol, h);   // h0[p]
        }
        if (p >= 1) {
            float gi = ps1[(jl)      * 129 + b_act] + ps1[2064 + (jl)      * 129 + b_act] + bs1[jl];
            float gf = ps1[(4 + jl)  * 129 + b_act] + ps1[2064 + (4 + jl)  * 129 + b_act] + bs1[4 + jl];
            float gg = ps1[(8 + jl)  * 129 + b_act] + ps1[2064 + (8 + jl)  * 129 + b_act] + bs1[8 + jl];
            float go = ps1[(12 + jl) * 129 + b_act] + ps1[2064 + (12 + jl) * 129 + b_act] + bs1[12 + jl];
            c1 = sigm(gf) * c1 + sigm(gi) * tanh_fast(gg);
            float h = sigm(go) * tanh_fast(c1);
            st2_agent(h1b + (size_t)((p + 7) & 7) * (NB * NH) + b_act * NH + hcol, h);  // h1[p-1]
        }

        // ---- barrier with overlap: arrive, next x-part during spin, wait+inv ----
        __syncthreads();                       // drains vmcnt: h-stores at LLC
        if (tid == 0) gbar_arrive(bar, (unsigned)(p + 1), wg);
        if (p + 1 < NT) xpart(p + 1);          // h-independent work hides spin
        if (tid == 0) gbar_wait(bar, (unsigned)(p + 1));
        __syncthreads();
    }

    // dense head, parallel over batch: WG b computes out[b][0..1] from h1[255]
    // (ring slot 7; agent inv at epoch 256 guarantees fresh refill)
    if (wg < NB) {
        const _Float16* hrow = h1b + (size_t)7 * (NB * NH) + wg * NH;
        float hk0 = (float)hrow[tid * 2];
        float hk1 = (float)hrow[tid * 2 + 1];
        float p0 = hk0 * Wd[tid * 2] + hk1 * Wd[tid * 2 + 1];
        float p1 = hk0 * Wd[NH + tid * 2] + hk1 * Wd[NH + tid * 2 + 1];
        #pragma unroll
        for (int off = 32; off; off >>= 1) {
            p0 += __shfl_down(p0, off);
            p1 += __shfl_down(p1, off);
        }
        float* red = ps0;  // scratch (all threads past final __syncthreads)
        if (lane == 0) { red[wave * 2] = p0; red[wave * 2 + 1] = p1; }
        __syncthreads();
        if (tid < 2) {
            float s = bd[tid];
            #pragma unroll
            for (int w = 0; w < 8; ++w) s += red[w * 2 + tid];
            out[wg * 2 + tid] = tanhf(s);
        }
    }
}

extern "C" void kernel_launch(void* const* d_in, const int* in_sizes, int n_in,
                              void* d_out, int out_size, void* d_ws, size_t ws_size,
                              hipStream_t stream) {
    const float* x    = (const float*)d_in[0];
    const float* Wih0 = (const float*)d_in[1];
    const float* Whh0 = (const float*)d_in[2];
    const float* bih0 = (const float*)d_in[3];
    const float* bhh0 = (const float*)d_in[4];
    const float* Wih1 = (const float*)d_in[5];
    const float* Whh1 = (const float*)d_in[6];
    const float* bih1 = (const float*)d_in[7];
    const float* bhh1 = (const float*)d_in[8];
    const float* Wd   = (const float*)d_in[9];
    const float* bd   = (const float*)d_in[10];
    float* out = (float*)d_out;
    char* ws = (char*)d_ws;

    hipFuncSetAttribute((const void*)lstm_persist,
                        hipFuncAttributeMaxDynamicSharedMemorySize, LDS_BYTES);

    void* kargs[] = { &x, &Wih0, &Whh0, &bih0, &bhh0, &Wih1, &Whh1, &bih1, &bhh1,
                      &Wd, &bd, &out, &ws };
    hipLaunchCooperativeKernel((void*)lstm_persist, dim3(256), dim3(512),
                               kargs, LDS_BYTES, stream);
}